// Round 6
// baseline (1106.286 us; speedup 1.0000x reference)
//
#include <hip/hip_runtime.h>

// OLSTM: T=20 frames, N=50000 nodes, K=10000 active peds/frame
// RNN=128, EMB=64, IN=2, OUT=5, G2=16
#define TT   20
#define NN   50000
#define KK   10000
#define RNN  128
#define EMB  64
#define GG2  16
#define NOUT 5
#define MPB  32                        // peds per block (2 MFMA m-tiles)
#define NTHR 512                       // 8 waves
#define NTILE ((KK + MPB - 1) / MPB)   // 313 (last tile ragged: 16 peds)

typedef __attribute__((ext_vector_type(8))) short bf16x8;
typedef __attribute__((ext_vector_type(4))) float f32x4;

__device__ __forceinline__ unsigned short f2b(float x) {  // fp32 -> bf16 bits, RNE
    union { float f; unsigned u; } v; v.f = x;
    return (unsigned short)((v.u + 0x7FFF + ((v.u >> 16) & 1)) >> 16);
}
__device__ __forceinline__ unsigned pack2(float a, float b) {
    return (unsigned)f2b(a) | ((unsigned)f2b(b) << 16);
}
__device__ __forceinline__ float sigf(float x)   { return 1.f / (1.f + __expf(-x)); }
__device__ __forceinline__ float tanh_f(float x) { return 2.f / (1.f + __expf(-2.f * x)) - 1.f; }

struct Params {
    const float* input_data; const float* grids;
    const float* h0; const float* c0;
    const int*   active_idx;
    const float* W_in;  const float* b_in;
    const float* W_obs; const float* b_obs;
    const float* W_ih;  const float* b_ih;
    const float* W_hh;  const float* b_hh;
    const float* W_out; const float* b_out;
    float* outputs; float* h_all; float* c_all;
    unsigned short* Wt; float* biasp; int* win;   // win: 2*NN ints (ping-pong)
    unsigned* bar;                                // hierarchical barrier counters
};

struct Smem {
    unsigned short uS[MPB][264];  // [ie(64) te(64) h(128)] bf16
    float cS[MPB][132];           // c state; reused in-place as h_new
    float gS[MPB][GG2];
    int s_idxbuf[2][MPB];         // double-buffered node ids (prefetch t+1)
    int s_win[MPB];
};

// bf16 transposed+permuted weights Wt[cp][k] (512x256) + fused bias (r5-proven):
// cp = 64*wq + 16*gate + cl  ->  orig col = 128*gate + 16*wq + cl.
// Consumer wave takes cp in [128*wc, 128*wc+128): ni = 4*rg+gate,
// r = 32*wc + 16*rg + cl  =>  lane-local i,f,g,o.
__global__ __launch_bounds__(256) void prep_kernel(
    const float* __restrict__ Wih, const float* __restrict__ Whh,
    const float* __restrict__ bih, const float* __restrict__ bhh,
    unsigned short* __restrict__ Wt, float* __restrict__ biasp)
{
    int cp = blockIdx.x;       // 0..511
    int k  = threadIdx.x;      // 0..255
    int wq = cp >> 6, rem = cp & 63, gate = rem >> 4, cl = rem & 15;
    int oc = 128 * gate + 16 * wq + cl;
    float v = (k < 128) ? Wih[k * 512 + oc] : Whh[(k - 128) * 512 + oc];
    Wt[cp * 256 + k] = f2b(v);
    if (k == 0) biasp[cp] = bih[oc] + bhh[oc];
}

__global__ __launch_bounds__(256) void init_kernel(
    const float* __restrict__ h0, const float* __restrict__ c0,
    const int* __restrict__ idx0,
    float* __restrict__ h_all, float* __restrict__ c_all, int* __restrict__ win0)
{
    int stride = gridDim.x * blockDim.x;
    int i = blockIdx.x * blockDim.x + threadIdx.x;
    for (int p = i; p < NN * RNN; p += stride) { h_all[p] = h0[p]; c_all[p] = c0[p]; }
    for (int p = i; p < KK; p += stride) atomicMax(&win0[idx0[p]], p);
}

// Hierarchical grid barrier, monotonic epochs (no reset, no wrap at 20 frames).
// Release arrive: drains vmcnt -> agent-scope (sc1) state stores are complete at
// the IF$ coherence point before the count ticks. Spin is relaxed agent loads
// (served by IF$, no local-cache invalidate => weights STAY cached in L2).
__device__ __forceinline__ void grid_barrier(unsigned* bar, unsigned epoch) {
    __syncthreads();
    if (threadIdx.x == 0) {
        unsigned g   = blockIdx.x & 7u;
        unsigned gsz = (gridDim.x - g + 7u) >> 3;   // #blocks with idx%8==g
        unsigned old = __hip_atomic_fetch_add(&bar[g * 32], 1u,
                          __ATOMIC_RELEASE, __HIP_MEMORY_SCOPE_AGENT);
        if (old + 1u == gsz * epoch)                // group leader for this epoch
            __hip_atomic_fetch_add(&bar[8 * 32], gsz,
                          __ATOMIC_RELEASE, __HIP_MEMORY_SCOPE_AGENT);
        while (__hip_atomic_load(&bar[8 * 32], __ATOMIC_RELAXED,
                          __HIP_MEMORY_SCOPE_AGENT) < gridDim.x * epoch)
            __builtin_amdgcn_s_sleep(2);
        __builtin_amdgcn_fence(__ATOMIC_ACQUIRE, "workgroup");  // compiler/lds order only
    }
    __syncthreads();
}

// One 32-ped tile of one frame. Cross-frame data (h/c state, win tags) moves via
// relaxed AGENT-scope atomics (coherent at IF$ regardless of XCD; r5-proven).
__device__ __forceinline__ void frame_body(const Params& P, Smem& S, int t,
                                           int buf, int has_next, int fresh) {
    const int tid = threadIdx.x;
    const int k0  = blockIdx.x * MPB;
    int* win_cur = P.win + (t & 1) * NN;
    int* win_nxt = P.win + ((t + 1) & 1) * NN;
    const int* s_idx = S.s_idxbuf[buf];

    if (fresh) {  // fallback path: no prefetched ids in LDS
        if (tid < MPB) {
            int k = k0 + tid;
            S.s_idxbuf[buf][tid] = (k < KK) ? P.active_idx[t * KK + k] : 0;
        }
        __syncthreads();
    }

    // ---- phase 0 (no block sync needed before gather: s_idx already valid) ----
    if (tid < MPB) {
        int k = k0 + tid;
        if (has_next) {  // prefetch t+1 ids + pass-1 winner atomics
            int nid = 0;
            if (k < KK) {
                nid = P.active_idx[(t + 1) * KK + k];
                atomicMax(&win_nxt[nid], (t + 1) * KK + k);
            }
            S.s_idxbuf[buf ^ 1][tid] = nid;
        }
    } else if (tid >= 64 && tid < 64 + MPB) {
        int m = tid - 64, k = k0 + m, wn = 0;
        if (k < KK) {
            int tag = __hip_atomic_load(&win_cur[s_idx[m]],
                         __ATOMIC_RELAXED, __HIP_MEMORY_SCOPE_AGENT);
            wn = (tag == t * KK + k) ? 1 : 0;
        }
        S.s_win[m] = wn;   // consumed after the pre-MFMA __syncthreads
    }
    {   // stage grid rows: 512 threads = 32 peds x 16 (wave-local producer/consumer)
        int m = tid >> 4, g = tid & 15;
        int kg = k0 + m; if (kg >= KK) kg = KK - 1;
        S.gS[m][g] = P.grids[((size_t)t * KK + kg) * GG2 + g];
    }
    // ---- gather h (->bf16) + c (fp32): 16 threads/ped, agent-coherent dword loads ----
    {
        int m = tid >> 4, l = tid & 15;
        int node = s_idx[m];
        const float* hp = P.h_all + (size_t)node * RNN + l * 8;
        const float* cp = P.c_all + (size_t)node * RNN + l * 8;
        float hv[8], cv[8];
        #pragma unroll
        for (int j = 0; j < 8; ++j)
            hv[j] = __hip_atomic_load(hp + j, __ATOMIC_RELAXED, __HIP_MEMORY_SCOPE_AGENT);
        #pragma unroll
        for (int j = 0; j < 8; ++j)
            cv[j] = __hip_atomic_load(cp + j, __ATOMIC_RELAXED, __HIP_MEMORY_SCOPE_AGENT);
        unsigned* du = (unsigned*)&S.uS[m][128 + l * 8];
        #pragma unroll
        for (int j = 0; j < 4; ++j) du[j] = pack2(hv[2 * j], hv[2 * j + 1]);
        #pragma unroll
        for (int j = 0; j < 8; ++j) S.cS[m][l * 8 + j] = cv[j];
    }
    // ---- embeddings: 16 threads/ped, 4 cols each (same-quarter-wave gS reuse) ----
    {
        int m = tid >> 4, e0 = (tid & 15) * 4;
        int node = s_idx[m];
        float x0 = P.input_data[((size_t)t * NN + node) * 2 + 0];
        float x1 = P.input_data[((size_t)t * NN + node) * 2 + 1];
        float iv[4], tv[4];
        #pragma unroll
        for (int j = 0; j < 4; ++j) {
            int e = e0 + j;
            iv[j] = fmaxf(fmaf(x0, P.W_in[e], fmaf(x1, P.W_in[64 + e], P.b_in[e])), 0.f);
            tv[j] = P.b_obs[e];
        }
        #pragma unroll
        for (int g = 0; g < GG2; ++g) {
            float gv = S.gS[m][g];
            #pragma unroll
            for (int j = 0; j < 4; ++j) tv[j] = fmaf(gv, P.W_obs[g * EMB + e0 + j], tv[j]);
        }
        unsigned* di = (unsigned*)&S.uS[m][e0];
        unsigned* dt = (unsigned*)&S.uS[m][64 + e0];
        di[0] = pack2(iv[0], iv[1]); di[1] = pack2(iv[2], iv[3]);
        dt[0] = pack2(fmaxf(tv[0], 0.f), fmaxf(tv[1], 0.f));
        dt[1] = pack2(fmaxf(tv[2], 0.f), fmaxf(tv[3], 0.f));
    }
    __syncthreads();

    // ---- gates GEMM: wave w = (m-tile mt, col-quarter wc); L2-resident Wt ----
    const int w = tid >> 6, lane = tid & 63;
    const int cl = lane & 15, kq = lane >> 4;
    const int wc = w & 3, mt = w >> 2;
    f32x4 acc[8];
    #pragma unroll
    for (int ni = 0; ni < 8; ++ni) {
        float bv = P.biasp[128 * wc + 16 * ni + cl];
        acc[ni] = (f32x4){bv, bv, bv, bv};
    }
    const unsigned short* Wb = P.Wt + ((size_t)(128 * wc + cl)) * 256 + kq * 8;
    #pragma unroll
    for (int ks = 0; ks < 8; ++ks) {
        const int kk = ks * 32;
        bf16x8 a = *(const bf16x8*)&S.uS[mt * 16 + cl][kk + kq * 8];
        #pragma unroll
        for (int ni = 0; ni < 8; ++ni) {
            bf16x8 bf = *(const bf16x8*)(Wb + (size_t)ni * 16 * 256 + kk);
            acc[ni] = __builtin_amdgcn_mfma_f32_16x16x32_bf16(a, bf, acc[ni], 0, 0, 0);
        }
    }

    // ---- LSTM: lane-local i,f,g,o; ped m = mt*16+4*kq+reg, unit r = 32*wc+16*rg+cl ----
    #pragma unroll
    for (int rg = 0; rg < 2; ++rg) {
        #pragma unroll
        for (int reg = 0; reg < 4; ++reg) {
            float iv = acc[4 * rg + 0][reg], fv = acc[4 * rg + 1][reg];
            float gv = acc[4 * rg + 2][reg], ov = acc[4 * rg + 3][reg];
            int m = mt * 16 + 4 * kq + reg;
            int r = 32 * wc + 16 * rg + cl;
            float cn = fmaf(sigf(fv), S.cS[m][r], sigf(iv) * tanh_f(gv));
            float hv = sigf(ov) * tanh_f(cn);
            S.cS[m][r] = hv;  // exclusive (m,r) per lane: in-place h_new
            if (S.s_win[m]) { // winners-only state update, agent-coherent stores
                int node = S.s_idxbuf[buf][m];
                __hip_atomic_store(&P.h_all[(size_t)node * RNN + r], hv,
                                   __ATOMIC_RELAXED, __HIP_MEMORY_SCOPE_AGENT);
                __hip_atomic_store(&P.c_all[(size_t)node * RNN + r], cn,
                                   __ATOMIC_RELAXED, __HIP_MEMORY_SCOPE_AGENT);
            }
        }
    }
    __syncthreads();  // h_new (in cS) visible block-wide

    // ---- out projection (winners only), h_new from LDS ----
    if (tid < MPB * NOUT) {
        int m = tid / NOUT, o = tid - m * NOUT;
        if (S.s_win[m]) {
            const float* hp = S.cS[m];
            float a0 = P.b_out[o], a1 = 0.f, a2 = 0.f, a3 = 0.f;
            #pragma unroll 4
            for (int r = 0; r < RNN; r += 4) {
                a0 = fmaf(hp[r],     P.W_out[(r)     * NOUT + o], a0);
                a1 = fmaf(hp[r + 1], P.W_out[(r + 1) * NOUT + o], a1);
                a2 = fmaf(hp[r + 2], P.W_out[(r + 2) * NOUT + o], a2);
                a3 = fmaf(hp[r + 3], P.W_out[(r + 3) * NOUT + o], a3);
            }
            P.outputs[((size_t)t * NN + S.s_idxbuf[buf][m]) * NOUT + o] = (a0 + a1) + (a2 + a3);
        }
    }
}

// Persistent kernel: one tile per block, hand-rolled barrier between frames.
__global__ __launch_bounds__(NTHR, 4) void persist_kernel(Params P) {
    __shared__ Smem S;
    if (threadIdx.x < MPB) {
        int k = blockIdx.x * MPB + threadIdx.x;
        S.s_idxbuf[0][threadIdx.x] = (k < KK) ? P.active_idx[k] : 0;
    }
    __syncthreads();
    for (int t = 0; t < TT; ++t) {
        frame_body(P, S, t, t & 1, (t + 1 < TT) ? 1 : 0, 0);
        if (t + 1 < TT) grid_barrier(P.bar, (unsigned)(t + 1));
    }
}

// Fallback: one frame per launch (kernel boundaries provide visibility).
__global__ __launch_bounds__(NTHR, 4) void step_kernel(Params P, int t, int has_next) {
    __shared__ Smem S;
    frame_body(P, S, t, 0, has_next, 1);
}

extern "C" void kernel_launch(void* const* d_in, const int* in_sizes, int n_in,
                              void* d_out, int out_size, void* d_ws, size_t ws_size,
                              hipStream_t stream) {
    Params P;
    P.input_data = (const float*)d_in[0];
    P.grids      = (const float*)d_in[1];
    P.h0         = (const float*)d_in[2];
    P.c0         = (const float*)d_in[3];
    P.active_idx = (const int*)d_in[4];
    P.W_in  = (const float*)d_in[5];
    P.b_in  = (const float*)d_in[6];
    P.W_obs = (const float*)d_in[7];
    P.b_obs = (const float*)d_in[8];
    P.W_ih  = (const float*)d_in[9];
    P.b_ih  = (const float*)d_in[10];
    P.W_hh  = (const float*)d_in[11];
    P.b_hh  = (const float*)d_in[12];
    P.W_out = (const float*)d_in[13];
    P.b_out = (const float*)d_in[14];

    // d_out: outputs[T*N*5] | h_fin[N*128] | c_fin[N*128] — state lives in place.
    P.outputs = (float*)d_out;
    P.h_all   = P.outputs + (size_t)TT * NN * NOUT;
    P.c_all   = P.h_all + (size_t)NN * RNN;

    // d_ws: win[2*N] ints | Wt bf16 512x256 | biasp[512] | bar[288]
    char* ws = (char*)d_ws;
    P.win   = (int*)ws;                                   ws += (size_t)2 * NN * sizeof(int);
    P.Wt    = (unsigned short*)ws;                        ws += (size_t)512 * 256 * sizeof(unsigned short);
    P.biasp = (float*)ws;                                 ws += 512 * sizeof(float);
    P.bar   = (unsigned*)ws;

    hipMemsetAsync(P.outputs, 0, (size_t)TT * NN * NOUT * sizeof(float), stream);
    hipMemsetAsync(P.win, 0xFF, (size_t)2 * NN * sizeof(int), stream);   // -1 everywhere
    hipMemsetAsync(P.bar, 0, 288 * sizeof(unsigned), stream);            // barrier epoch 0
    prep_kernel<<<512, 256, 0, stream>>>(P.W_ih, P.W_hh, P.b_ih, P.b_hh, P.Wt, P.biasp);
    init_kernel<<<1024, 256, 0, stream>>>(P.h0, P.c0, P.active_idx, P.h_all, P.c_all, P.win);

    int maxB = 0;
    hipError_t qe = hipOccupancyMaxActiveBlocksPerMultiprocessor(&maxB, persist_kernel, NTHR, 0);
    int ncu = 0, dev = 0;
    hipGetDevice(&dev);
    if (hipDeviceGetAttribute(&ncu, hipDeviceAttributeMultiprocessorCount, dev) != hipSuccess || ncu <= 0)
        ncu = 256;
    hipError_t le = hipErrorUnknown;
    if (qe == hipSuccess && maxB * ncu >= NTILE) {   // all 313 blocks must be co-resident
        void* kargs[] = { (void*)&P };
        le = hipLaunchCooperativeKernel((const void*)persist_kernel, dim3(NTILE), dim3(NTHR),
                                        kargs, 0, stream);
    }
    if (le != hipSuccess) {
        (void)hipGetLastError();  // clear; proven per-frame path
        for (int t = 0; t < TT; ++t)
            step_kernel<<<NTILE, NTHR, 0, stream>>>(P, t, (t + 1 < TT) ? 1 : 0);
    }
}

// Round 7
// 749.241 us; speedup vs baseline: 1.4765x; 1.4765x over previous
//
#include <hip/hip_runtime.h>

// OLSTM: T=20 frames, N=50000 nodes, K=10000 active peds/frame
// RNN=128, EMB=64, IN=2, OUT=5, G2=16
//
// Architecture (round 7): node-ownership partitioning. Block b owns nodes
// [98b, 98b+98). A binning pass routes each (t,k) ped to its owner block, so
// h/c state is LDS-resident for all 20 frames, winner resolution is LDS-local,
// and there is NO inter-block communication: no barriers, no fences, no
// per-frame launches. Global traffic = weights (L2-resident, streamed), grids/x,
// one-time state load/writeback, outputs.
#define TT    20
#define NN    50000
#define KK    10000
#define RNN   128
#define EMB   64
#define GG2   16
#define NOUT  5
#define NODEB 98
#define NBLK  ((NN + NODEB - 1) / NODEB)   // 511 blocks (block 510 owns 20 nodes)
#define CAP   64                           // peds per (frame, block); E[n]=19.6, P(>64)~1e-15
#define NTHR  512                          // 8 waves

typedef __attribute__((ext_vector_type(8))) short bf16x8;
typedef __attribute__((ext_vector_type(4))) float f32x4;

__device__ __forceinline__ unsigned short f2b(float x) {  // fp32 -> bf16, RNE
    union { float f; unsigned u; } v; v.f = x;
    return (unsigned short)((v.u + 0x7FFF + ((v.u >> 16) & 1)) >> 16);
}
__device__ __forceinline__ unsigned pack2(float a, float b) {
    return (unsigned)f2b(a) | ((unsigned)f2b(b) << 16);
}
__device__ __forceinline__ float sigf(float x)   { return 1.f / (1.f + __expf(-x)); }
__device__ __forceinline__ float tanh_f(float x) { return 2.f / (1.f + __expf(-2.f * x)) - 1.f; }

struct Params {
    const float* input_data; const float* grids;
    const float* h0; const float* c0;
    const int*   active_idx;
    const float* W_in;  const float* b_in;
    const float* W_obs; const float* b_obs;
    const float* W_out; const float* b_out;
    float* outputs; float* h_all; float* c_all;
    unsigned short* Wt; float* biasp;
    int* cnt; int* lists;          // binning: cnt[TT*NBLK], lists[TT*NBLK*CAP]
};

struct SmemT {
    float hS[NODEB][132];          // owned h state, fp32 (pad 132: bank spread)
    float cS[NODEB][132];          // owned c state, fp32
    unsigned short uS[32][264];    // GEMM A: [ie(64) te(64) h(128)] bf16, 32-ped super-tile
    float gX[32][20];              // per-winner staged grid row (16) + x (2)
    int eL[2][CAP];                // double-buffered entry lists
    int wL[CAP];                   // winner entries
    int wslot[NODEB];              // winner tags per node-local
    int s_cnt[2];
    int s_wn;
};

// bf16 transposed+permuted weights Wt[cp][k] (512x256) + fused bias (r2/r6-proven):
// cp = 64*wq + 16*gate + cl  ->  orig col = 128*gate + 16*wq + cl.
// Consumer wave w takes cp in [64w, 64w+64): its 4 n-tiles = gates i,f,g,o for
// rnn unit r = 16w + cl  =>  lane-local LSTM.
__global__ __launch_bounds__(256) void prep_kernel(
    const float* __restrict__ Wih, const float* __restrict__ Whh,
    const float* __restrict__ bih, const float* __restrict__ bhh,
    unsigned short* __restrict__ Wt, float* __restrict__ biasp)
{
    int cp = blockIdx.x;       // 0..511
    int k  = threadIdx.x;      // 0..255
    int wq = cp >> 6, rem = cp & 63, gate = rem >> 4, cl = rem & 15;
    int oc = 128 * gate + 16 * wq + cl;
    float v = (k < 128) ? Wih[k * 512 + oc] : Whh[(k - 128) * 512 + oc];
    Wt[cp * 256 + k] = f2b(v);
    if (k == 0) biasp[cp] = bih[oc] + bhh[oc];
}

// Bin each (t,k) ped to its node-owner block. Entry = k | (node_local << 14).
__global__ __launch_bounds__(256) void bin_kernel(
    const int* __restrict__ idx, int* __restrict__ cnt, int* __restrict__ lists)
{
    int e = blockIdx.x * 256 + threadIdx.x;
    if (e >= TT * KK) return;
    int t = e / KK, k = e - t * KK;
    int nd = idx[e];
    int ow = nd / NODEB, nl = nd - ow * NODEB;
    int slot = atomicAdd(&cnt[t * NBLK + ow], 1);
    if (slot < CAP) lists[((size_t)(t * NBLK + ow)) * CAP + slot] = k | (nl << 14);
}

__global__ __launch_bounds__(NTHR, 1) void olstm_kernel(Params P) {
    extern __shared__ char smem_raw[];
    SmemT& S = *(SmemT*)smem_raw;
    const int tid = threadIdx.x;
    const int b   = blockIdx.x;
    const int n0  = b * NODEB;
    const int nown = (NN - n0 < NODEB) ? (NN - n0) : NODEB;

    // ---- prologue: owned state -> LDS (coalesced), frame-0 entries ----
    for (int i = tid; i < nown * RNN; i += NTHR) {
        int nl = i >> 7, r = i & 127;
        S.hS[nl][r] = P.h0[(size_t)n0 * RNN + i];
        S.cS[nl][r] = P.c0[(size_t)n0 * RNN + i];
    }
    if (tid == 0) { int c = P.cnt[b]; S.s_cnt[0] = (c > CAP) ? CAP : c; }
    if (tid < CAP) S.eL[0][tid] = P.lists[(size_t)b * CAP + tid];
    __syncthreads();

    const int w = tid >> 6, lane = tid & 63;
    const int cl = lane & 15, kq = lane >> 4;

    for (int t = 0; t < TT; ++t) {
        const int buf = t & 1;
        // prefetch t+1 entry list into regs (committed at frame end)
        int pf_e = 0, pf_c = 0;
        if (t + 1 < TT) {
            if (tid < CAP) pf_e = P.lists[((size_t)((t + 1) * NBLK + b)) * CAP + tid];
            if (tid == 0)  pf_c = P.cnt[(t + 1) * NBLK + b];
        }
        const int cn = S.s_cnt[buf];
        // ---- winner resolution (LDS-local: all peds of a node are in this block) ----
        if (tid < nown) S.wslot[tid] = -1;
        if (tid == 0) S.s_wn = 0;
        __syncthreads();
        int ent = 0, mk = -1, mnl = 0;
        if (tid < cn) {
            ent = S.eL[buf][tid]; mnl = ent >> 14; mk = ent & 0x3FFF;
            atomicMax(&S.wslot[mnl], mk);
        }
        __syncthreads();
        if (tid < cn && S.wslot[mnl] == mk) {
            int slot = atomicAdd(&S.s_wn, 1);
            S.wL[slot] = ent;
        }
        __syncthreads();
        const int wn = S.s_wn;

        for (int base = 0; base < wn; base += 32) {
            const int ms = (wn - base < 32) ? (wn - base) : 32;
            // ---- issue x + grid loads into regs (latency overlapped with h-fill) ----
            float2 xv = {0.f, 0.f};
            float4 gv = {0.f, 0.f, 0.f, 0.f};
            if (tid < 32) {
                if (tid < ms) {
                    int ee = S.wL[base + tid];
                    int nn = n0 + (ee >> 14);
                    xv = *(const float2*)(P.input_data + ((size_t)t * NN + nn) * 2);
                }
            } else if (tid < 160) {
                int j = tid - 32, m = j >> 2, q = j & 3;
                int mm = (m < ms) ? m : 0;
                int kk2 = S.wL[base + mm] & 0x3FFF;
                gv = *(const float4*)(P.grids + ((size_t)t * KK + kk2) * GG2 + q * 4);
            }
            // ---- uS h-part from LDS state (bf16), zero-pad dummy rows ----
            {
                int m = tid >> 4, l = tid & 15;
                unsigned* du = (unsigned*)&S.uS[m][128 + l * 8];
                if (m < ms) {
                    int nl2 = S.wL[base + m] >> 14;
                    const float* hp = &S.hS[nl2][l * 8];
                    du[0] = pack2(hp[0], hp[1]); du[1] = pack2(hp[2], hp[3]);
                    du[2] = pack2(hp[4], hp[5]); du[3] = pack2(hp[6], hp[7]);
                } else { du[0] = 0; du[1] = 0; du[2] = 0; du[3] = 0; }
            }
            // commit staged loads
            if (tid < 32) { S.gX[tid][16] = xv.x; S.gX[tid][17] = xv.y; }
            else if (tid < 160) {
                int j = tid - 32, m = j >> 2, q = j & 3;
                S.gX[m][q * 4 + 0] = gv.x; S.gX[m][q * 4 + 1] = gv.y;
                S.gX[m][q * 4 + 2] = gv.z; S.gX[m][q * 4 + 3] = gv.w;
            }
            __syncthreads();
            // ---- embeddings: 16 thr/ped, 4 cols each ----
            {
                int m = tid >> 4, e0 = (tid & 15) * 4;
                unsigned* di = (unsigned*)&S.uS[m][e0];
                unsigned* dt = (unsigned*)&S.uS[m][64 + e0];
                if (m < ms) {
                    float x0 = S.gX[m][16], x1 = S.gX[m][17];
                    float iv[4], tv[4];
                    #pragma unroll
                    for (int j = 0; j < 4; ++j) {
                        int e = e0 + j;
                        iv[j] = fmaxf(fmaf(x0, P.W_in[e], fmaf(x1, P.W_in[64 + e], P.b_in[e])), 0.f);
                        tv[j] = P.b_obs[e];
                    }
                    #pragma unroll
                    for (int g = 0; g < GG2; ++g) {
                        float gg = S.gX[m][g];
                        #pragma unroll
                        for (int j = 0; j < 4; ++j) tv[j] = fmaf(gg, P.W_obs[g * EMB + e0 + j], tv[j]);
                    }
                    di[0] = pack2(iv[0], iv[1]); di[1] = pack2(iv[2], iv[3]);
                    dt[0] = pack2(fmaxf(tv[0], 0.f), fmaxf(tv[1], 0.f));
                    dt[1] = pack2(fmaxf(tv[2], 0.f), fmaxf(tv[3], 0.f));
                } else { di[0] = 0; di[1] = 0; dt[0] = 0; dt[1] = 0; }
            }
            __syncthreads();

            // ---- gates GEMM: wave w covers permuted cols [64w, 64w+64), 2 m-tiles ----
            f32x4 acc[2][4];
            #pragma unroll
            for (int gate = 0; gate < 4; ++gate) {
                float bv = P.biasp[64 * w + 16 * gate + cl];
                acc[0][gate] = (f32x4){bv, bv, bv, bv};
                acc[1][gate] = acc[0][gate];
            }
            const unsigned short* Wb = P.Wt + ((size_t)(64 * w + cl)) * 256 + kq * 8;
            #pragma unroll
            for (int ks = 0; ks < 8; ++ks) {
                const int kk = ks * 32;
                bf16x8 a0 = *(const bf16x8*)&S.uS[cl][kk + kq * 8];
                bf16x8 a1 = *(const bf16x8*)&S.uS[16 + cl][kk + kq * 8];
                #pragma unroll
                for (int gate = 0; gate < 4; ++gate) {
                    bf16x8 bf = *(const bf16x8*)(Wb + (size_t)gate * 16 * 256 + kk);
                    acc[0][gate] = __builtin_amdgcn_mfma_f32_16x16x32_bf16(a0, bf, acc[0][gate], 0, 0, 0);
                    acc[1][gate] = __builtin_amdgcn_mfma_f32_16x16x32_bf16(a1, bf, acc[1][gate], 0, 0, 0);
                }
            }
            // ---- LSTM: lane-local i,f,g,o; ped m = mt*16+4kq+reg, unit r = 16w+cl ----
            const int r = 16 * w + cl;
            #pragma unroll
            for (int mt = 0; mt < 2; ++mt) {
                #pragma unroll
                for (int reg = 0; reg < 4; ++reg) {
                    int m = mt * 16 + 4 * kq + reg;
                    if (m < ms) {
                        int nl2 = S.wL[base + m] >> 14;
                        float iv = acc[mt][0][reg], fv = acc[mt][1][reg];
                        float gg = acc[mt][2][reg], ov = acc[mt][3][reg];
                        float cn2 = fmaf(sigf(fv), S.cS[nl2][r], sigf(iv) * tanh_f(gg));
                        float hv = sigf(ov) * tanh_f(cn2);
                        S.hS[nl2][r] = hv;   // exclusive (node, r) per lane
                        S.cS[nl2][r] = cn2;
                    }
                }
            }
            __syncthreads();  // h_new visible for out-proj
            // ---- out projection (winners, i.e. all processed rows) ----
            if (tid < ms * NOUT) {
                int m = tid / NOUT, o = tid - m * NOUT;
                int nl2 = S.wL[base + m] >> 14;
                const float* hp = S.hS[nl2];
                float a0 = P.b_out[o], a1 = 0.f, a2 = 0.f, a3 = 0.f;
                #pragma unroll 4
                for (int rr = 0; rr < RNN; rr += 4) {
                    a0 = fmaf(hp[rr],     P.W_out[(rr)     * NOUT + o], a0);
                    a1 = fmaf(hp[rr + 1], P.W_out[(rr + 1) * NOUT + o], a1);
                    a2 = fmaf(hp[rr + 2], P.W_out[(rr + 2) * NOUT + o], a2);
                    a3 = fmaf(hp[rr + 3], P.W_out[(rr + 3) * NOUT + o], a3);
                }
                P.outputs[((size_t)t * NN + n0 + nl2) * NOUT + o] = (a0 + a1) + (a2 + a3);
            }
            __syncthreads();  // uS/gX reusable
        }

        // commit prefetched t+1 entries
        if (t + 1 < TT) {
            if (tid < CAP) S.eL[buf ^ 1][tid] = pf_e;
            if (tid == 0)  S.s_cnt[buf ^ 1] = (pf_c > CAP) ? CAP : pf_c;
        }
        __syncthreads();
    }

    // ---- epilogue: state writeback (coalesced) ----
    for (int i = tid; i < nown * RNN; i += NTHR) {
        int nl = i >> 7, r = i & 127;
        P.h_all[(size_t)n0 * RNN + i] = S.hS[nl][r];
        P.c_all[(size_t)n0 * RNN + i] = S.cS[nl][r];
    }
}

extern "C" void kernel_launch(void* const* d_in, const int* in_sizes, int n_in,
                              void* d_out, int out_size, void* d_ws, size_t ws_size,
                              hipStream_t stream) {
    Params P;
    P.input_data = (const float*)d_in[0];
    P.grids      = (const float*)d_in[1];
    P.h0         = (const float*)d_in[2];
    P.c0         = (const float*)d_in[3];
    P.active_idx = (const int*)d_in[4];
    P.W_in  = (const float*)d_in[5];
    P.b_in  = (const float*)d_in[6];
    P.W_obs = (const float*)d_in[7];
    P.b_obs = (const float*)d_in[8];
    const float* W_ih = (const float*)d_in[9];
    const float* b_ih = (const float*)d_in[10];
    const float* W_hh = (const float*)d_in[11];
    const float* b_hh = (const float*)d_in[12];
    P.W_out = (const float*)d_in[13];
    P.b_out = (const float*)d_in[14];

    // d_out: outputs[T*N*5] | h_fin[N*128] | c_fin[N*128]
    P.outputs = (float*)d_out;
    P.h_all   = P.outputs + (size_t)TT * NN * NOUT;
    P.c_all   = P.h_all + (size_t)NN * RNN;

    // d_ws: Wt (512x256 bf16, 262144 B) | biasp (2048 B) | cnt (TT*NBLK) | lists (TT*NBLK*CAP)
    char* ws = (char*)d_ws;
    P.Wt    = (unsigned short*)ws;            ws += (size_t)512 * 256 * sizeof(unsigned short);
    P.biasp = (float*)ws;                     ws += 512 * sizeof(float);
    P.cnt   = (int*)ws;                       ws += (size_t)TT * NBLK * sizeof(int);
    P.lists = (int*)ws;

    hipMemsetAsync(P.outputs, 0, (size_t)TT * NN * NOUT * sizeof(float), stream);
    hipMemsetAsync(P.cnt, 0, (size_t)TT * NBLK * sizeof(int), stream);
    prep_kernel<<<512, 256, 0, stream>>>(W_ih, W_hh, b_ih, b_hh, P.Wt, P.biasp);
    bin_kernel<<<(TT * KK + 255) / 256, 256, 0, stream>>>(P.active_idx, P.cnt, P.lists);

    // 124 KB dynamic LDS (gfx950 has 160 KB/CU); attribute raise is host-side, capture-safe
    int smem = (int)sizeof(SmemT);
    hipFuncSetAttribute((const void*)olstm_kernel,
                        hipFuncAttributeMaxDynamicSharedMemorySize, smem);
    olstm_kernel<<<NBLK, NTHR, smem, stream>>>(P);
}